// Round 7
// baseline (178.485 us; speedup 1.0000x reference)
//
#include <hip/hip_runtime.h>

#define NN 50000
#define EE 800000
#define FF 128
#define OO 64
#define EPSF 1e-5f
#define SCB 196    // ceil(NN / 256)
#define EBLK 3125  // EE / 256
#define GBLK 391   // ceil(NN / 128)

typedef unsigned int uint;
typedef unsigned short ushort;
typedef __attribute__((ext_vector_type(8))) short short8;  // 8 bf16 = 4 VGPR
typedef __attribute__((ext_vector_type(4))) float f32x4;

// ---- bf16 helpers (RTNE pack, cheap unpack) ----
__device__ __forceinline__ float bflo(uint v) { return __uint_as_float(v << 16); }
__device__ __forceinline__ float bfhi(uint v) { return __uint_as_float(v & 0xFFFF0000u); }
__device__ __forceinline__ uint f2bf(float f) {
  uint b = __float_as_uint(f);
  return (b + 0x7FFFu + ((b >> 16) & 1u)) >> 16;
}
__device__ __forceinline__ uint pack2(float x, float y) { return f2bf(x) | (f2bf(y) << 16); }

// ---- edge-index access: handles both int32 and int64 serialized layouts ----
__device__ __forceinline__ int eidx(const void* ei, long long pos, int f64) {
  if (f64) return (int)((const long long*)ei)[pos];
  return ((const int*)ei)[pos];
}

// fused: zero cnt + detect int64-vs-int32 layout
__global__ void k_init(const void* ei, int* flag, int* cnt) {
  int i = blockIdx.x * 256 + threadIdx.x;
  if (i < NN) cnt[i] = 0;
  if (i == 0) {
    const int* p = (const int*)ei;
    int any = 0;
    for (int j = 1; j < 128; j += 2) any |= p[j];  // high words all 0 <=> int64
    *flag = (any == 0) ? 1 : 0;
  }
}

// one thread per edge: count degree AND record this edge's rank within its dst row
__global__ void k_deg_rank(const void* ei, const int* __restrict__ flag,
                           int* __restrict__ cnt, int* __restrict__ rank) {
  int e = blockIdx.x * 256 + threadIdx.x;
  if (e >= EE) return;
  int f64 = *flag;
  int d = eidx(ei, (long long)EE + e, f64);
  rank[e] = atomicAdd(&cnt[d], 1);
}

// fused: dis = rsqrt(deg+1) + per-block partial sums for the scan
__global__ __launch_bounds__(256) void k_dis_part(const int* __restrict__ cnt,
                                                  float* __restrict__ dis,
                                                  int* __restrict__ bsum) {
  int i = blockIdx.x * 256 + threadIdx.x;
  int v = (i < NN) ? cnt[i] : 0;
  if (i < NN) dis[i] = rsqrtf((float)(v + 1));  // +1 self-loop, always > 0
  int s = v;
#pragma unroll
  for (int m = 1; m < 64; m <<= 1) s += __shfl_xor(s, m);
  __shared__ int ws[4];
  if ((threadIdx.x & 63) == 0) ws[threadIdx.x >> 6] = s;
  __syncthreads();
  if (threadIdx.x == 0) bsum[blockIdx.x] = ws[0] + ws[1] + ws[2] + ws[3];
}

__global__ __launch_bounds__(256) void k_scan_tops(const int* __restrict__ bsum,
                                                   int* __restrict__ boff,
                                                   int* __restrict__ rowptr) {
  __shared__ int s[256];
  int tid = threadIdx.x;
  int v = (tid < SCB) ? bsum[tid] : 0;
  s[tid] = v;
  __syncthreads();
  for (int off = 1; off < 256; off <<= 1) {
    int t = (tid >= off) ? s[tid - off] : 0;
    __syncthreads();
    s[tid] += t;
    __syncthreads();
  }
  if (tid < SCB) boff[tid] = s[tid] - v;  // exclusive
  if (tid == 255) rowptr[NN] = s[255];    // total = EE
}

__global__ __launch_bounds__(256) void k_scan_write(const int* __restrict__ cnt,
                                                    const int* __restrict__ boff,
                                                    int* __restrict__ rowptr) {
  int blk = blockIdx.x, tid = threadIdx.x;
  int i = blk * 256 + tid;
  int v = (i < NN) ? cnt[i] : 0;
  int lane = tid & 63, wid = tid >> 6;
  int inc = v;
#pragma unroll
  for (int off = 1; off < 64; off <<= 1) {
    int t = __shfl_up(inc, off);
    if (lane >= off) inc += t;
  }
  __shared__ int wsum[4];
  if (lane == 63) wsum[wid] = inc;
  __syncthreads();
  int wadd = 0;
  for (int wj = 0; wj < wid; ++wj) wadd += wsum[wj];
  int exc = inc - v + wadd + boff[blk];
  if (i < NN) rowptr[i] = exc;
}

// atomic-free scatter: cw[rowptr[d]+rank[e]] = (src, dis[src]*dis[dst])
__global__ void k_scatter(const void* ei, const int* __restrict__ flag,
                          const float* __restrict__ dis,
                          const int* __restrict__ rowptr,
                          const int* __restrict__ rank,
                          int2* __restrict__ cw) {
  int e = blockIdx.x * 256 + threadIdx.x;
  if (e >= EE) return;
  int f64 = *flag;
  int s = eidx(ei, e, f64);
  int d = eidx(ei, (long long)EE + e, f64);
  int p = rowptr[d] + rank[e];
  int2 v;
  v.x = s;
  v.y = __float_as_int(dis[s] * dis[d]);
  cw[p] = v;
}

// swizzled LDS index for Wt[c][k] (ushort units): c*128 + (k ^ ((c&7)<<3))
__device__ __forceinline__ int wt_idx(int c, int k) {
  return c * 128 + (k ^ ((c & 7) << 3));
}

// ---- MFMA GEMM 1: T(bf16)[N][128] = X(f32) @ W1(f32->bf16) ----
__global__ __launch_bounds__(256) void k_gemm1(const float* __restrict__ X,
                                               const float* __restrict__ W,
                                               ushort* __restrict__ T) {
  __shared__ ushort Wt[FF * FF];  // 32 KB, Wt[c][k] swizzled
  for (int i = threadIdx.x; i < FF * FF; i += 256) {
    int k = i >> 7, c = i & 127;
    Wt[wt_idx(c, k)] = (ushort)f2bf(W[i]);
  }
  __syncthreads();
  int l = threadIdx.x & 63, wv = threadIdx.x >> 6;
  int rbase = blockIdx.x * 128 + wv * 32;
  int lr = l & 15, lk = (l >> 4) << 3;
  f32x4 acc[2][8] = {};
#pragma unroll
  for (int kb = 0; kb < 4; ++kb) {
    int kk = kb * 32 + lk;
    short8 a[2];
#pragma unroll
    for (int rt = 0; rt < 2; ++rt) {
      int row = min(rbase + rt * 16 + lr, NN - 1);
      const float4* ap = (const float4*)(X + (size_t)row * FF + kk);
      float4 x0 = ap[0], x1 = ap[1];
      a[rt][0] = (short)f2bf(x0.x); a[rt][1] = (short)f2bf(x0.y);
      a[rt][2] = (short)f2bf(x0.z); a[rt][3] = (short)f2bf(x0.w);
      a[rt][4] = (short)f2bf(x1.x); a[rt][5] = (short)f2bf(x1.y);
      a[rt][6] = (short)f2bf(x1.z); a[rt][7] = (short)f2bf(x1.w);
    }
#pragma unroll
    for (int ct = 0; ct < 8; ++ct) {
      int c = ct * 16 + lr;
      short8 b = *(const short8*)&Wt[wt_idx(c, kk)];
      acc[0][ct] = __builtin_amdgcn_mfma_f32_16x16x32_bf16(a[0], b, acc[0][ct], 0, 0, 0);
      acc[1][ct] = __builtin_amdgcn_mfma_f32_16x16x32_bf16(a[1], b, acc[1][ct], 0, 0, 0);
    }
  }
  int rl = (l >> 4) * 4;  // C/D: col = lane&15, row = (lane>>4)*4 + reg
#pragma unroll
  for (int rt = 0; rt < 2; ++rt)
#pragma unroll
    for (int reg = 0; reg < 4; ++reg) {
      int row = rbase + rt * 16 + rl + reg;
      if (row < NN) {
#pragma unroll
        for (int ct = 0; ct < 8; ++ct)
          T[(size_t)row * FF + ct * 16 + lr] = (ushort)f2bf(acc[rt][ct][reg]);
      }
    }
}

// ---- MFMA GEMM 2: out = A(bf16) @ [Wmu|Wlv] + [bmu|blv], split store ----
__global__ __launch_bounds__(256) void k_gemm2(const ushort* __restrict__ A,
                                               const float* __restrict__ Wmu,
                                               const float* __restrict__ bmu,
                                               const float* __restrict__ Wlv,
                                               const float* __restrict__ blv,
                                               float* __restrict__ out) {
  __shared__ ushort Wt[FF * FF];
  __shared__ float sb[FF];
  for (int i = threadIdx.x; i < FF * FF; i += 256) {
    int k = i >> 7, c = i & 127;
    float v = (c < OO) ? Wmu[k * OO + c] : Wlv[k * OO + (c - OO)];
    Wt[wt_idx(c, k)] = (ushort)f2bf(v);
  }
  if (threadIdx.x < FF)
    sb[threadIdx.x] = (threadIdx.x < OO) ? bmu[threadIdx.x] : blv[threadIdx.x - OO];
  __syncthreads();
  int l = threadIdx.x & 63, wv = threadIdx.x >> 6;
  int rbase = blockIdx.x * 128 + wv * 32;
  int lr = l & 15, lk = (l >> 4) << 3;
  f32x4 acc[2][8] = {};
#pragma unroll
  for (int kb = 0; kb < 4; ++kb) {
    int kk = kb * 32 + lk;
    short8 a[2];
#pragma unroll
    for (int rt = 0; rt < 2; ++rt) {
      int row = min(rbase + rt * 16 + lr, NN - 1);
      a[rt] = *(const short8*)(A + (size_t)row * FF + kk);
    }
#pragma unroll
    for (int ct = 0; ct < 8; ++ct) {
      int c = ct * 16 + lr;
      short8 b = *(const short8*)&Wt[wt_idx(c, kk)];
      acc[0][ct] = __builtin_amdgcn_mfma_f32_16x16x32_bf16(a[0], b, acc[0][ct], 0, 0, 0);
      acc[1][ct] = __builtin_amdgcn_mfma_f32_16x16x32_bf16(a[1], b, acc[1][ct], 0, 0, 0);
    }
  }
  int rl = (l >> 4) * 4;
#pragma unroll
  for (int rt = 0; rt < 2; ++rt)
#pragma unroll
    for (int reg = 0; reg < 4; ++reg) {
      int row = rbase + rt * 16 + rl + reg;
      if (row < NN) {
#pragma unroll
        for (int ct = 0; ct < 8; ++ct) {
          int c = ct * 16 + lr;
          float v = acc[rt][ct][reg] + sb[c];
          if (ct < 4) out[(size_t)row * OO + c] = v;                    // mu
          else out[(size_t)NN * OO + (size_t)row * OO + (c - OO)] = v;  // logvar
        }
      }
    }
}

// persistent waves, 16-deep load batches for MLP
// LN=1: fused bias+ReLU+LayerNorm epilogue (conv1); LN=0: raw write (conv2)
template <int LN>
__global__ __launch_bounds__(256) void k_gather(const int* __restrict__ rowptr,
                                                const int2* __restrict__ cw,
                                                const float* __restrict__ dis,
                                                const ushort* __restrict__ feat,
                                                const float* __restrict__ b1,
                                                const float* __restrict__ gamma,
                                                const float* __restrict__ beta,
                                                ushort* __restrict__ outp) {
  int gw = (blockIdx.x * 256 + threadIdx.x) >> 6;
  int nw = (gridDim.x * 256) >> 6;
  int lane = threadIdx.x & 63;
  for (int node = gw; node < NN; node += nw) {
    float di = dis[node];
    float sw = di * di;
    uint sv = ((const uint*)(feat + ((size_t)node << 7)))[lane];
    float ax = sw * bflo(sv), ay = sw * bfhi(sv);
    int e = rowptr[node], end = rowptr[node + 1];
    while (end - e >= 16) {
      int2 c[16];
      uint v[16];
#pragma unroll
      for (int j = 0; j < 16; ++j) c[j] = cw[e + j];
#pragma unroll
      for (int j = 0; j < 16; ++j) v[j] = ((const uint*)(feat + ((size_t)c[j].x << 7)))[lane];
#pragma unroll
      for (int j = 0; j < 16; ++j) {
        float wj = __int_as_float(c[j].y);
        ax = fmaf(wj, bflo(v[j]), ax); ay = fmaf(wj, bfhi(v[j]), ay);
      }
      e += 16;
    }
    if (end - e >= 8) {
      int2 c[8];
      uint v[8];
#pragma unroll
      for (int j = 0; j < 8; ++j) c[j] = cw[e + j];
#pragma unroll
      for (int j = 0; j < 8; ++j) v[j] = ((const uint*)(feat + ((size_t)c[j].x << 7)))[lane];
#pragma unroll
      for (int j = 0; j < 8; ++j) {
        float wj = __int_as_float(c[j].y);
        ax = fmaf(wj, bflo(v[j]), ax); ay = fmaf(wj, bfhi(v[j]), ay);
      }
      e += 8;
    }
    if (end - e >= 4) {
      int2 c[4];
      uint v[4];
#pragma unroll
      for (int j = 0; j < 4; ++j) c[j] = cw[e + j];
#pragma unroll
      for (int j = 0; j < 4; ++j) v[j] = ((const uint*)(feat + ((size_t)c[j].x << 7)))[lane];
#pragma unroll
      for (int j = 0; j < 4; ++j) {
        float wj = __int_as_float(c[j].y);
        ax = fmaf(wj, bflo(v[j]), ax); ay = fmaf(wj, bfhi(v[j]), ay);
      }
      e += 4;
    }
    for (; e < end; ++e) {
      int2 c0 = cw[e];
      uint v0 = ((const uint*)(feat + ((size_t)c0.x << 7)))[lane];
      float w0 = __int_as_float(c0.y);
      ax = fmaf(w0, bflo(v0), ax); ay = fmaf(w0, bfhi(v0), ay);
    }
    float ox, oy;
    if (LN) {
      float b0 = b1[2 * lane], b1v = b1[2 * lane + 1];
      float a0 = fmaxf(ax + b0, 0.f);
      float a1 = fmaxf(ay + b1v, 0.f);
      float s = a0 + a1, sq = a0 * a0 + a1 * a1;
#pragma unroll
      for (int m = 1; m < 64; m <<= 1) {
        s += __shfl_xor(s, m);
        sq += __shfl_xor(sq, m);
      }
      float mean = s * (1.f / 128.f);
      float var = sq * (1.f / 128.f) - mean * mean;
      float rstd = rsqrtf(var + EPSF);
      float g0 = gamma[2 * lane], g1 = gamma[2 * lane + 1];
      float be0 = beta[2 * lane], be1 = beta[2 * lane + 1];
      ox = (a0 - mean) * rstd * g0 + be0;
      oy = (a1 - mean) * rstd * g1 + be1;
    } else {
      ox = ax; oy = ay;
    }
    ((uint*)(outp + ((size_t)node << 7)))[lane] = pack2(ox, oy);
  }
}

extern "C" void kernel_launch(void* const* d_in, const int* in_sizes, int n_in,
                              void* d_out, int out_size, void* d_ws, size_t ws_size,
                              hipStream_t stream) {
  const float* x     = (const float*)d_in[0];
  const void*  ei    = d_in[1];
  const float* W1    = (const float*)d_in[2];
  const float* b1    = (const float*)d_in[3];
  const float* gamma = (const float*)d_in[4];
  const float* beta  = (const float*)d_in[5];
  const float* Wmu   = (const float*)d_in[6];
  const float* bmu   = (const float*)d_in[7];
  const float* Wlv   = (const float*)d_in[8];
  const float* blv   = (const float*)d_in[9];
  float* out = (float*)d_out;

  // workspace (4B words):
  // [flag 64][cnt N][rowptr N+16][dis N][bsum 256][boff 256][rank E]
  // [cw int2 E][t bf16 N*128][h bf16 N*128][t2 bf16 N*128]   ~48.6 MB
  int*   flag   = (int*)d_ws;
  int*   cnt    = flag + 64;
  int*   rowptr = cnt + NN;
  float* dis    = (float*)(rowptr + (NN + 16));
  int*   bsum   = (int*)(dis + NN);
  int*   boff   = bsum + 256;
  int*   rank   = boff + 256;
  size_t off32  = (size_t)(64 + NN + (NN + 16) + NN + 256 + 256 + EE);
  off32 = (off32 + 63) & ~(size_t)63;
  int2*  cw     = (int2*)((int*)d_ws + off32);
  ushort* t  = (ushort*)(cw + EE);
  ushort* h  = t + (size_t)NN * FF;
  ushort* t2 = h + (size_t)NN * FF;

  k_init<<<SCB, 256, 0, stream>>>(ei, flag, cnt);
  k_deg_rank<<<EBLK, 256, 0, stream>>>(ei, flag, cnt, rank);
  k_dis_part<<<SCB, 256, 0, stream>>>(cnt, dis, bsum);
  k_scan_tops<<<1, 256, 0, stream>>>(bsum, boff, rowptr);
  k_scan_write<<<SCB, 256, 0, stream>>>(cnt, boff, rowptr);
  k_scatter<<<EBLK, 256, 0, stream>>>(ei, flag, dis, rowptr, rank, cw);

  k_gemm1<<<GBLK, 256, 0, stream>>>(x, W1, t);
  k_gather<1><<<2048, 256, 0, stream>>>(rowptr, cw, dis, t, b1, gamma, beta, h);
  k_gather<0><<<2048, 256, 0, stream>>>(rowptr, cw, dis, h, b1, gamma, beta, t2);
  k_gemm2<<<GBLK, 256, 0, stream>>>(t2, Wmu, bmu, Wlv, blv, out);
}

// Round 8
// 165.887 us; speedup vs baseline: 1.0759x; 1.0759x over previous
//
#include <hip/hip_runtime.h>

#define NN 50000
#define EE 800000
#define FF 128
#define OO 64
#define EPSF 1e-5f
#define SCB 196    // ceil(NN / 256)
#define EBLK 3125  // EE / 256
#define GBLK 391   // ceil(NN / 128)

typedef unsigned int uint;
typedef unsigned short ushort;
typedef __attribute__((ext_vector_type(8))) short short8;  // 8 bf16 = 4 VGPR
typedef __attribute__((ext_vector_type(4))) float f32x4;

// ---- bf16 helpers (RTNE pack, cheap unpack) ----
__device__ __forceinline__ float bflo(uint v) { return __uint_as_float(v << 16); }
__device__ __forceinline__ float bfhi(uint v) { return __uint_as_float(v & 0xFFFF0000u); }
__device__ __forceinline__ uint f2bf(float f) {
  uint b = __float_as_uint(f);
  return (b + 0x7FFFu + ((b >> 16) & 1u)) >> 16;
}
__device__ __forceinline__ uint pack2(float x, float y) { return f2bf(x) | (f2bf(y) << 16); }

// ---- edge-index access: handles both int32 and int64 serialized layouts ----
__device__ __forceinline__ int eidx(const void* ei, long long pos, int f64) {
  if (f64) return (int)((const long long*)ei)[pos];
  return ((const int*)ei)[pos];
}

// fused: zero cnt + detect int64-vs-int32 layout
__global__ void k_init(const void* ei, int* flag, int* cnt) {
  int i = blockIdx.x * 256 + threadIdx.x;
  if (i < NN) cnt[i] = 0;
  if (i == 0) {
    const int* p = (const int*)ei;
    int any = 0;
    for (int j = 1; j < 128; j += 2) any |= p[j];  // high words all 0 <=> int64
    *flag = (any == 0) ? 1 : 0;
  }
}

// one thread per edge: count degree AND record this edge's rank within its dst row
__global__ void k_deg_rank(const void* ei, const int* __restrict__ flag,
                           int* __restrict__ cnt, int* __restrict__ rank) {
  int e = blockIdx.x * 256 + threadIdx.x;
  if (e >= EE) return;
  int f64 = *flag;
  int d = eidx(ei, (long long)EE + e, f64);
  rank[e] = atomicAdd(&cnt[d], 1);
}

// fused: dis = rsqrt(deg+1) + per-block partial sums for the scan
__global__ __launch_bounds__(256) void k_dis_part(const int* __restrict__ cnt,
                                                  float* __restrict__ dis,
                                                  int* __restrict__ bsum) {
  int i = blockIdx.x * 256 + threadIdx.x;
  int v = (i < NN) ? cnt[i] : 0;
  if (i < NN) dis[i] = rsqrtf((float)(v + 1));  // +1 self-loop, always > 0
  int s = v;
#pragma unroll
  for (int m = 1; m < 64; m <<= 1) s += __shfl_xor(s, m);
  __shared__ int ws[4];
  if ((threadIdx.x & 63) == 0) ws[threadIdx.x >> 6] = s;
  __syncthreads();
  if (threadIdx.x == 0) bsum[blockIdx.x] = ws[0] + ws[1] + ws[2] + ws[3];
}

__global__ __launch_bounds__(256) void k_scan_tops(const int* __restrict__ bsum,
                                                   int* __restrict__ boff,
                                                   int* __restrict__ rowptr) {
  __shared__ int s[256];
  int tid = threadIdx.x;
  int v = (tid < SCB) ? bsum[tid] : 0;
  s[tid] = v;
  __syncthreads();
  for (int off = 1; off < 256; off <<= 1) {
    int t = (tid >= off) ? s[tid - off] : 0;
    __syncthreads();
    s[tid] += t;
    __syncthreads();
  }
  if (tid < SCB) boff[tid] = s[tid] - v;  // exclusive
  if (tid == 255) rowptr[NN] = s[255];    // total = EE
}

__global__ __launch_bounds__(256) void k_scan_write(const int* __restrict__ cnt,
                                                    const int* __restrict__ boff,
                                                    int* __restrict__ rowptr) {
  int blk = blockIdx.x, tid = threadIdx.x;
  int i = blk * 256 + tid;
  int v = (i < NN) ? cnt[i] : 0;
  int lane = tid & 63, wid = tid >> 6;
  int inc = v;
#pragma unroll
  for (int off = 1; off < 64; off <<= 1) {
    int t = __shfl_up(inc, off);
    if (lane >= off) inc += t;
  }
  __shared__ int wsum[4];
  if (lane == 63) wsum[wid] = inc;
  __syncthreads();
  int wadd = 0;
  for (int wj = 0; wj < wid; ++wj) wadd += wsum[wj];
  int exc = inc - v + wadd + boff[blk];
  if (i < NN) rowptr[i] = exc;
}

// atomic-free scatter: cw[rowptr[d]+rank[e]] = (src, dis[src]*dis[dst])
__global__ void k_scatter(const void* ei, const int* __restrict__ flag,
                          const float* __restrict__ dis,
                          const int* __restrict__ rowptr,
                          const int* __restrict__ rank,
                          int2* __restrict__ cw) {
  int e = blockIdx.x * 256 + threadIdx.x;
  if (e >= EE) return;
  int f64 = *flag;
  int s = eidx(ei, e, f64);
  int d = eidx(ei, (long long)EE + e, f64);
  int p = rowptr[d] + rank[e];
  int2 v;
  v.x = s;
  v.y = __float_as_int(dis[s] * dis[d]);
  cw[p] = v;
}

// swizzled LDS index for Wt[c][k] (ushort units): c*128 + (k ^ ((c&7)<<3))
__device__ __forceinline__ int wt_idx(int c, int k) {
  return c * 128 + (k ^ ((c & 7) << 3));
}

// ---- MFMA GEMM 1: T(bf16)[N][128] = X(f32) @ W1(f32->bf16) ----
__global__ __launch_bounds__(256) void k_gemm1(const float* __restrict__ X,
                                               const float* __restrict__ W,
                                               ushort* __restrict__ T) {
  __shared__ ushort Wt[FF * FF];  // 32 KB, Wt[c][k] swizzled
  for (int i = threadIdx.x; i < FF * FF; i += 256) {
    int k = i >> 7, c = i & 127;
    Wt[wt_idx(c, k)] = (ushort)f2bf(W[i]);
  }
  __syncthreads();
  int l = threadIdx.x & 63, wv = threadIdx.x >> 6;
  int rbase = blockIdx.x * 128 + wv * 32;
  int lr = l & 15, lk = (l >> 4) << 3;
  f32x4 acc[2][8] = {};
#pragma unroll
  for (int kb = 0; kb < 4; ++kb) {
    int kk = kb * 32 + lk;
    short8 a[2];
#pragma unroll
    for (int rt = 0; rt < 2; ++rt) {
      int row = min(rbase + rt * 16 + lr, NN - 1);
      const float4* ap = (const float4*)(X + (size_t)row * FF + kk);
      float4 x0 = ap[0], x1 = ap[1];
      a[rt][0] = (short)f2bf(x0.x); a[rt][1] = (short)f2bf(x0.y);
      a[rt][2] = (short)f2bf(x0.z); a[rt][3] = (short)f2bf(x0.w);
      a[rt][4] = (short)f2bf(x1.x); a[rt][5] = (short)f2bf(x1.y);
      a[rt][6] = (short)f2bf(x1.z); a[rt][7] = (short)f2bf(x1.w);
    }
#pragma unroll
    for (int ct = 0; ct < 8; ++ct) {
      int c = ct * 16 + lr;
      short8 b = *(const short8*)&Wt[wt_idx(c, kk)];
      acc[0][ct] = __builtin_amdgcn_mfma_f32_16x16x32_bf16(a[0], b, acc[0][ct], 0, 0, 0);
      acc[1][ct] = __builtin_amdgcn_mfma_f32_16x16x32_bf16(a[1], b, acc[1][ct], 0, 0, 0);
    }
  }
  int rl = (l >> 4) * 4;  // C/D: col = lane&15, row = (lane>>4)*4 + reg
#pragma unroll
  for (int rt = 0; rt < 2; ++rt)
#pragma unroll
    for (int reg = 0; reg < 4; ++reg) {
      int row = rbase + rt * 16 + rl + reg;
      if (row < NN) {
#pragma unroll
        for (int ct = 0; ct < 8; ++ct)
          T[(size_t)row * FF + ct * 16 + lr] = (ushort)f2bf(acc[rt][ct][reg]);
      }
    }
}

// ---- MFMA GEMM 2: out = A(bf16) @ [Wmu|Wlv] + [bmu|blv], split store ----
__global__ __launch_bounds__(256) void k_gemm2(const ushort* __restrict__ A,
                                               const float* __restrict__ Wmu,
                                               const float* __restrict__ bmu,
                                               const float* __restrict__ Wlv,
                                               const float* __restrict__ blv,
                                               float* __restrict__ out) {
  __shared__ ushort Wt[FF * FF];
  __shared__ float sb[FF];
  for (int i = threadIdx.x; i < FF * FF; i += 256) {
    int k = i >> 7, c = i & 127;
    float v = (c < OO) ? Wmu[k * OO + c] : Wlv[k * OO + (c - OO)];
    Wt[wt_idx(c, k)] = (ushort)f2bf(v);
  }
  if (threadIdx.x < FF)
    sb[threadIdx.x] = (threadIdx.x < OO) ? bmu[threadIdx.x] : blv[threadIdx.x - OO];
  __syncthreads();
  int l = threadIdx.x & 63, wv = threadIdx.x >> 6;
  int rbase = blockIdx.x * 128 + wv * 32;
  int lr = l & 15, lk = (l >> 4) << 3;
  f32x4 acc[2][8] = {};
#pragma unroll
  for (int kb = 0; kb < 4; ++kb) {
    int kk = kb * 32 + lk;
    short8 a[2];
#pragma unroll
    for (int rt = 0; rt < 2; ++rt) {
      int row = min(rbase + rt * 16 + lr, NN - 1);
      a[rt] = *(const short8*)(A + (size_t)row * FF + kk);
    }
#pragma unroll
    for (int ct = 0; ct < 8; ++ct) {
      int c = ct * 16 + lr;
      short8 b = *(const short8*)&Wt[wt_idx(c, kk)];
      acc[0][ct] = __builtin_amdgcn_mfma_f32_16x16x32_bf16(a[0], b, acc[0][ct], 0, 0, 0);
      acc[1][ct] = __builtin_amdgcn_mfma_f32_16x16x32_bf16(a[1], b, acc[1][ct], 0, 0, 0);
    }
  }
  int rl = (l >> 4) * 4;
#pragma unroll
  for (int rt = 0; rt < 2; ++rt)
#pragma unroll
    for (int reg = 0; reg < 4; ++reg) {
      int row = rbase + rt * 16 + rl + reg;
      if (row < NN) {
#pragma unroll
        for (int ct = 0; ct < 8; ++ct) {
          int c = ct * 16 + lr;
          float v = acc[rt][ct][reg] + sb[c];
          if (ct < 4) out[(size_t)row * OO + c] = v;                    // mu
          else out[(size_t)NN * OO + (size_t)row * OO + (c - OO)] = v;  // logvar
        }
      }
    }
}

// one wave per node; lane l: edge-slot g=l>>4, column-chunk c16=l&15 (16B of row).
// 4 edge rows per VMEM instruction (1 KiB), 8 edges in flight.
// LN=1: fused bias+ReLU+LayerNorm epilogue (conv1); LN=0: raw write (conv2)
template <int LN>
__global__ __launch_bounds__(256) void k_gather(const int* __restrict__ rowptr,
                                                const int2* __restrict__ cw,
                                                const float* __restrict__ dis,
                                                const ushort* __restrict__ feat,
                                                const float* __restrict__ b1,
                                                const float* __restrict__ gamma,
                                                const float* __restrict__ beta,
                                                ushort* __restrict__ outp) {
  int node = blockIdx.x * 4 + (threadIdx.x >> 6);
  if (node >= NN) return;
  int l = threadIdx.x & 63;
  int g = l >> 4;    // edge slot within wave
  int c16 = l & 15;  // 16-byte column chunk

  float acc[8] = {};
  int e0 = rowptr[node], nE = rowptr[node + 1] - e0;
  int base = 0;
  for (; base + 8 <= nE; base += 8) {
    int2 cA = cw[e0 + base + g];
    int2 cB = cw[e0 + base + 4 + g];
    uint4 vA = ((const uint4*)(feat + ((size_t)cA.x << 7)))[c16];
    uint4 vB = ((const uint4*)(feat + ((size_t)cB.x << 7)))[c16];
    float wA = __int_as_float(cA.y), wB = __int_as_float(cB.y);
    acc[0] = fmaf(wA, bflo(vA.x), acc[0]); acc[1] = fmaf(wA, bfhi(vA.x), acc[1]);
    acc[2] = fmaf(wA, bflo(vA.y), acc[2]); acc[3] = fmaf(wA, bfhi(vA.y), acc[3]);
    acc[4] = fmaf(wA, bflo(vA.z), acc[4]); acc[5] = fmaf(wA, bfhi(vA.z), acc[5]);
    acc[6] = fmaf(wA, bflo(vA.w), acc[6]); acc[7] = fmaf(wA, bfhi(vA.w), acc[7]);
    acc[0] = fmaf(wB, bflo(vB.x), acc[0]); acc[1] = fmaf(wB, bfhi(vB.x), acc[1]);
    acc[2] = fmaf(wB, bflo(vB.y), acc[2]); acc[3] = fmaf(wB, bfhi(vB.y), acc[3]);
    acc[4] = fmaf(wB, bflo(vB.z), acc[4]); acc[5] = fmaf(wB, bfhi(vB.z), acc[5]);
    acc[6] = fmaf(wB, bflo(vB.w), acc[6]); acc[7] = fmaf(wB, bfhi(vB.w), acc[7]);
  }
  // tail (0..7 edges): slots base+g and base+4+g
#pragma unroll
  for (int t = 0; t < 2; ++t) {
    int idx = base + t * 4 + g;
    if (idx < nE) {
      int2 c0 = cw[e0 + idx];
      uint4 v = ((const uint4*)(feat + ((size_t)c0.x << 7)))[c16];
      float w0 = __int_as_float(c0.y);
      acc[0] = fmaf(w0, bflo(v.x), acc[0]); acc[1] = fmaf(w0, bfhi(v.x), acc[1]);
      acc[2] = fmaf(w0, bflo(v.y), acc[2]); acc[3] = fmaf(w0, bfhi(v.y), acc[3]);
      acc[4] = fmaf(w0, bflo(v.z), acc[4]); acc[5] = fmaf(w0, bfhi(v.z), acc[5]);
      acc[6] = fmaf(w0, bflo(v.w), acc[6]); acc[7] = fmaf(w0, bfhi(v.w), acc[7]);
    }
  }
  // reduce across the 4 edge-slot groups (bits 4,5 of lane)
#pragma unroll
  for (int j = 0; j < 8; ++j) {
    acc[j] += __shfl_xor(acc[j], 16);
    acc[j] += __shfl_xor(acc[j], 32);
  }
  // self-loop (post-reduction so it's added once)
  {
    float di = dis[node];
    float sw = di * di;
    uint4 v = ((const uint4*)(feat + ((size_t)node << 7)))[c16];
    acc[0] = fmaf(sw, bflo(v.x), acc[0]); acc[1] = fmaf(sw, bfhi(v.x), acc[1]);
    acc[2] = fmaf(sw, bflo(v.y), acc[2]); acc[3] = fmaf(sw, bfhi(v.y), acc[3]);
    acc[4] = fmaf(sw, bflo(v.z), acc[4]); acc[5] = fmaf(sw, bfhi(v.z), acc[5]);
    acc[6] = fmaf(sw, bflo(v.w), acc[6]); acc[7] = fmaf(sw, bfhi(v.w), acc[7]);
  }
  int cOff = c16 * 8;
  float o[8];
  if (LN) {
    float4 ba = *(const float4*)&b1[cOff];
    float4 bb = *(const float4*)&b1[cOff + 4];
    float a[8];
    a[0] = fmaxf(acc[0] + ba.x, 0.f); a[1] = fmaxf(acc[1] + ba.y, 0.f);
    a[2] = fmaxf(acc[2] + ba.z, 0.f); a[3] = fmaxf(acc[3] + ba.w, 0.f);
    a[4] = fmaxf(acc[4] + bb.x, 0.f); a[5] = fmaxf(acc[5] + bb.y, 0.f);
    a[6] = fmaxf(acc[6] + bb.z, 0.f); a[7] = fmaxf(acc[7] + bb.w, 0.f);
    float s = 0.f, sq = 0.f;
#pragma unroll
    for (int j = 0; j < 8; ++j) { s += a[j]; sq += a[j] * a[j]; }
#pragma unroll
    for (int m = 1; m < 16; m <<= 1) {
      s += __shfl_xor(s, m);
      sq += __shfl_xor(sq, m);
    }
    float mean = s * (1.f / 128.f);
    float var = sq * (1.f / 128.f) - mean * mean;
    float rstd = rsqrtf(var + EPSF);
    float4 ga = *(const float4*)&gamma[cOff];
    float4 gb = *(const float4*)&gamma[cOff + 4];
    float4 ea = *(const float4*)&beta[cOff];
    float4 eb = *(const float4*)&beta[cOff + 4];
    o[0] = (a[0] - mean) * rstd * ga.x + ea.x; o[1] = (a[1] - mean) * rstd * ga.y + ea.y;
    o[2] = (a[2] - mean) * rstd * ga.z + ea.z; o[3] = (a[3] - mean) * rstd * ga.w + ea.w;
    o[4] = (a[4] - mean) * rstd * gb.x + eb.x; o[5] = (a[5] - mean) * rstd * gb.y + eb.y;
    o[6] = (a[6] - mean) * rstd * gb.z + eb.z; o[7] = (a[7] - mean) * rstd * gb.w + eb.w;
  } else {
#pragma unroll
    for (int j = 0; j < 8; ++j) o[j] = acc[j];
  }
  if (g == 0) {
    uint4 p;
    p.x = pack2(o[0], o[1]); p.y = pack2(o[2], o[3]);
    p.z = pack2(o[4], o[5]); p.w = pack2(o[6], o[7]);
    ((uint4*)(outp + ((size_t)node << 7)))[c16] = p;
  }
}

extern "C" void kernel_launch(void* const* d_in, const int* in_sizes, int n_in,
                              void* d_out, int out_size, void* d_ws, size_t ws_size,
                              hipStream_t stream) {
  const float* x     = (const float*)d_in[0];
  const void*  ei    = d_in[1];
  const float* W1    = (const float*)d_in[2];
  const float* b1    = (const float*)d_in[3];
  const float* gamma = (const float*)d_in[4];
  const float* beta  = (const float*)d_in[5];
  const float* Wmu   = (const float*)d_in[6];
  const float* bmu   = (const float*)d_in[7];
  const float* Wlv   = (const float*)d_in[8];
  const float* blv   = (const float*)d_in[9];
  float* out = (float*)d_out;

  // workspace (4B words):
  // [flag 64][cnt N][rowptr N+16][dis N][bsum 256][boff 256][rank E]
  // [cw int2 E][t bf16 N*128][h bf16 N*128][t2 bf16 N*128]   ~48.6 MB
  int*   flag   = (int*)d_ws;
  int*   cnt    = flag + 64;
  int*   rowptr = cnt + NN;
  float* dis    = (float*)(rowptr + (NN + 16));
  int*   bsum   = (int*)(dis + NN);
  int*   boff   = bsum + 256;
  int*   rank   = boff + 256;
  size_t off32  = (size_t)(64 + NN + (NN + 16) + NN + 256 + 256 + EE);
  off32 = (off32 + 63) & ~(size_t)63;
  int2*  cw     = (int2*)((int*)d_ws + off32);
  ushort* t  = (ushort*)(cw + EE);
  ushort* h  = t + (size_t)NN * FF;
  ushort* t2 = h + (size_t)NN * FF;

  k_init<<<SCB, 256, 0, stream>>>(ei, flag, cnt);
  k_deg_rank<<<EBLK, 256, 0, stream>>>(ei, flag, cnt, rank);
  k_dis_part<<<SCB, 256, 0, stream>>>(cnt, dis, bsum);
  k_scan_tops<<<1, 256, 0, stream>>>(bsum, boff, rowptr);
  k_scan_write<<<SCB, 256, 0, stream>>>(cnt, boff, rowptr);
  k_scatter<<<EBLK, 256, 0, stream>>>(ei, flag, dis, rowptr, rank, cw);

  k_gemm1<<<GBLK, 256, 0, stream>>>(x, W1, t);
  k_gather<1><<<(NN + 3) / 4, 256, 0, stream>>>(rowptr, cw, dis, t, b1, gamma, beta, h);
  k_gather<0><<<(NN + 3) / 4, 256, 0, stream>>>(rowptr, cw, dis, h, b1, gamma, beta, t2);
  k_gemm2<<<GBLK, 256, 0, stream>>>(t2, Wmu, bmu, Wlv, blv, out);
}

// Round 9
// 156.515 us; speedup vs baseline: 1.1404x; 1.0599x over previous
//
#include <hip/hip_runtime.h>

#define NN 50000
#define EE 800000
#define FF 128
#define OO 64
#define EPSF 1e-5f
#define SCB 196    // ceil(NN / 256)
#define EBLK 3125  // EE / 256
#define GBLK 391   // ceil(NN / 128)

typedef unsigned int uint;
typedef unsigned short ushort;
typedef __attribute__((ext_vector_type(8))) short short8;  // 8 bf16 = 4 VGPR
typedef __attribute__((ext_vector_type(4))) float f32x4;

// ---- bf16 helpers (RTNE pack, cheap unpack) ----
__device__ __forceinline__ float bflo(uint v) { return __uint_as_float(v << 16); }
__device__ __forceinline__ float bfhi(uint v) { return __uint_as_float(v & 0xFFFF0000u); }
__device__ __forceinline__ uint f2bf(float f) {
  uint b = __float_as_uint(f);
  return (b + 0x7FFFu + ((b >> 16) & 1u)) >> 16;
}
__device__ __forceinline__ uint pack2(float x, float y) { return f2bf(x) | (f2bf(y) << 16); }

// ---- edge-index access: handles both int32 and int64 serialized layouts ----
__device__ __forceinline__ int eidx(const void* ei, long long pos, int f64) {
  if (f64) return (int)((const long long*)ei)[pos];
  return ((const int*)ei)[pos];
}

// fused: zero cnt + detect int64-vs-int32 layout
__global__ void k_init(const void* ei, int* flag, int* cnt) {
  int i = blockIdx.x * 256 + threadIdx.x;
  if (i < NN) cnt[i] = 0;
  if (i == 0) {
    const int* p = (const int*)ei;
    int any = 0;
    for (int j = 1; j < 128; j += 2) any |= p[j];  // high words all 0 <=> int64
    *flag = (any == 0) ? 1 : 0;
  }
}

// one thread per edge: count degree AND record this edge's rank within its dst row
__global__ void k_deg_rank(const void* ei, const int* __restrict__ flag,
                           int* __restrict__ cnt, int* __restrict__ rank) {
  int e = blockIdx.x * 256 + threadIdx.x;
  if (e >= EE) return;
  int f64 = *flag;
  int d = eidx(ei, (long long)EE + e, f64);
  rank[e] = atomicAdd(&cnt[d], 1);
}

// fused: dis = rsqrt(deg+1) + per-block partial sums for the scan
__global__ __launch_bounds__(256) void k_dis_part(const int* __restrict__ cnt,
                                                  float* __restrict__ dis,
                                                  int* __restrict__ bsum) {
  int i = blockIdx.x * 256 + threadIdx.x;
  int v = (i < NN) ? cnt[i] : 0;
  if (i < NN) dis[i] = rsqrtf((float)(v + 1));  // +1 self-loop, always > 0
  int s = v;
#pragma unroll
  for (int m = 1; m < 64; m <<= 1) s += __shfl_xor(s, m);
  __shared__ int ws[4];
  if ((threadIdx.x & 63) == 0) ws[threadIdx.x >> 6] = s;
  __syncthreads();
  if (threadIdx.x == 0) bsum[blockIdx.x] = ws[0] + ws[1] + ws[2] + ws[3];
}

__global__ __launch_bounds__(256) void k_scan_tops(const int* __restrict__ bsum,
                                                   int* __restrict__ boff,
                                                   int* __restrict__ rowptr) {
  __shared__ int s[256];
  int tid = threadIdx.x;
  int v = (tid < SCB) ? bsum[tid] : 0;
  s[tid] = v;
  __syncthreads();
  for (int off = 1; off < 256; off <<= 1) {
    int t = (tid >= off) ? s[tid - off] : 0;
    __syncthreads();
    s[tid] += t;
    __syncthreads();
  }
  if (tid < SCB) boff[tid] = s[tid] - v;  // exclusive
  if (tid == 255) rowptr[NN] = s[255];    // total = EE
}

__global__ __launch_bounds__(256) void k_scan_write(const int* __restrict__ cnt,
                                                    const int* __restrict__ boff,
                                                    int* __restrict__ rowptr) {
  int blk = blockIdx.x, tid = threadIdx.x;
  int i = blk * 256 + tid;
  int v = (i < NN) ? cnt[i] : 0;
  int lane = tid & 63, wid = tid >> 6;
  int inc = v;
#pragma unroll
  for (int off = 1; off < 64; off <<= 1) {
    int t = __shfl_up(inc, off);
    if (lane >= off) inc += t;
  }
  __shared__ int wsum[4];
  if (lane == 63) wsum[wid] = inc;
  __syncthreads();
  int wadd = 0;
  for (int wj = 0; wj < wid; ++wj) wadd += wsum[wj];
  int exc = inc - v + wadd + boff[blk];
  if (i < NN) rowptr[i] = exc;
}

// swizzled LDS index for Wt[c][k] (ushort units): c*128 + (k ^ ((c&7)<<3))
__device__ __forceinline__ int wt_idx(int c, int k) {
  return c * 128 + (k ^ ((c & 7) << 3));
}

// ---- DUAL-ROLE kernel: blocks [0,GBLK) run MFMA GEMM1; blocks [GBLK,GBLK+EBLK)
// run the atomic-free CSR scatter. Disjoint resources (MFMA/LDS vs mem-latency),
// no data dependency -> scatter hides under GEMM.
__global__ __launch_bounds__(256) void k_scatter_gemm1(
    const void* ei, const int* __restrict__ flag, const float* __restrict__ dis,
    const int* __restrict__ rowptr, const int* __restrict__ rank,
    int2* __restrict__ cw,
    const float* __restrict__ X, const float* __restrict__ W,
    ushort* __restrict__ T) {
  __shared__ ushort Wt[FF * FF];  // 32 KB (allocated for all blocks; caps 5 blk/CU)
  if (blockIdx.x >= GBLK) {
    // ---- scatter role: cw[rowptr[d]+rank[e]] = (src, dis[src]*dis[dst]) ----
    int e = (blockIdx.x - GBLK) * 256 + threadIdx.x;
    if (e >= EE) return;
    int f64 = *flag;
    int s = eidx(ei, e, f64);
    int d = eidx(ei, (long long)EE + e, f64);
    int p = rowptr[d] + rank[e];
    int2 v;
    v.x = s;
    v.y = __float_as_int(dis[s] * dis[d]);
    cw[p] = v;
    return;
  }
  // ---- GEMM1 role: T(bf16)[N][128] = X(f32) @ W1(f32->bf16) ----
  for (int i = threadIdx.x; i < FF * FF; i += 256) {
    int k = i >> 7, c = i & 127;
    Wt[wt_idx(c, k)] = (ushort)f2bf(W[i]);
  }
  __syncthreads();
  int l = threadIdx.x & 63, wv = threadIdx.x >> 6;
  int rbase = blockIdx.x * 128 + wv * 32;
  int lr = l & 15, lk = (l >> 4) << 3;
  f32x4 acc[2][8] = {};
#pragma unroll
  for (int kb = 0; kb < 4; ++kb) {
    int kk = kb * 32 + lk;
    short8 a[2];
#pragma unroll
    for (int rt = 0; rt < 2; ++rt) {
      int row = min(rbase + rt * 16 + lr, NN - 1);
      const float4* ap = (const float4*)(X + (size_t)row * FF + kk);
      float4 x0 = ap[0], x1 = ap[1];
      a[rt][0] = (short)f2bf(x0.x); a[rt][1] = (short)f2bf(x0.y);
      a[rt][2] = (short)f2bf(x0.z); a[rt][3] = (short)f2bf(x0.w);
      a[rt][4] = (short)f2bf(x1.x); a[rt][5] = (short)f2bf(x1.y);
      a[rt][6] = (short)f2bf(x1.z); a[rt][7] = (short)f2bf(x1.w);
    }
#pragma unroll
    for (int ct = 0; ct < 8; ++ct) {
      int c = ct * 16 + lr;
      short8 b = *(const short8*)&Wt[wt_idx(c, kk)];
      acc[0][ct] = __builtin_amdgcn_mfma_f32_16x16x32_bf16(a[0], b, acc[0][ct], 0, 0, 0);
      acc[1][ct] = __builtin_amdgcn_mfma_f32_16x16x32_bf16(a[1], b, acc[1][ct], 0, 0, 0);
    }
  }
  int rl = (l >> 4) * 4;  // C/D: col = lane&15, row = (lane>>4)*4 + reg
#pragma unroll
  for (int rt = 0; rt < 2; ++rt)
#pragma unroll
    for (int reg = 0; reg < 4; ++reg) {
      int row = rbase + rt * 16 + rl + reg;
      if (row < NN) {
#pragma unroll
        for (int ct = 0; ct < 8; ++ct)
          T[(size_t)row * FF + ct * 16 + lr] = (ushort)f2bf(acc[rt][ct][reg]);
      }
    }
}

// ---- MFMA GEMM 2: out = A(bf16) @ [Wmu|Wlv] + [bmu|blv], split store ----
__global__ __launch_bounds__(256) void k_gemm2(const ushort* __restrict__ A,
                                               const float* __restrict__ Wmu,
                                               const float* __restrict__ bmu,
                                               const float* __restrict__ Wlv,
                                               const float* __restrict__ blv,
                                               float* __restrict__ out) {
  __shared__ ushort Wt[FF * FF];
  __shared__ float sb[FF];
  for (int i = threadIdx.x; i < FF * FF; i += 256) {
    int k = i >> 7, c = i & 127;
    float v = (c < OO) ? Wmu[k * OO + c] : Wlv[k * OO + (c - OO)];
    Wt[wt_idx(c, k)] = (ushort)f2bf(v);
  }
  if (threadIdx.x < FF)
    sb[threadIdx.x] = (threadIdx.x < OO) ? bmu[threadIdx.x] : blv[threadIdx.x - OO];
  __syncthreads();
  int l = threadIdx.x & 63, wv = threadIdx.x >> 6;
  int rbase = blockIdx.x * 128 + wv * 32;
  int lr = l & 15, lk = (l >> 4) << 3;
  f32x4 acc[2][8] = {};
#pragma unroll
  for (int kb = 0; kb < 4; ++kb) {
    int kk = kb * 32 + lk;
    short8 a[2];
#pragma unroll
    for (int rt = 0; rt < 2; ++rt) {
      int row = min(rbase + rt * 16 + lr, NN - 1);
      a[rt] = *(const short8*)(A + (size_t)row * FF + kk);
    }
#pragma unroll
    for (int ct = 0; ct < 8; ++ct) {
      int c = ct * 16 + lr;
      short8 b = *(const short8*)&Wt[wt_idx(c, kk)];
      acc[0][ct] = __builtin_amdgcn_mfma_f32_16x16x32_bf16(a[0], b, acc[0][ct], 0, 0, 0);
      acc[1][ct] = __builtin_amdgcn_mfma_f32_16x16x32_bf16(a[1], b, acc[1][ct], 0, 0, 0);
    }
  }
  int rl = (l >> 4) * 4;
#pragma unroll
  for (int rt = 0; rt < 2; ++rt)
#pragma unroll
    for (int reg = 0; reg < 4; ++reg) {
      int row = rbase + rt * 16 + rl + reg;
      if (row < NN) {
#pragma unroll
        for (int ct = 0; ct < 8; ++ct) {
          int c = ct * 16 + lr;
          float v = acc[rt][ct][reg] + sb[c];
          if (ct < 4) out[(size_t)row * OO + c] = v;                    // mu
          else out[(size_t)NN * OO + (size_t)row * OO + (c - OO)] = v;  // logvar
        }
      }
    }
}

// one wave per node; lane l: edge-slot g=l>>4, column-chunk c16=l&15 (16B of row).
// 4 edge rows per VMEM instruction (1 KiB), 8 edges in flight; self-row hoisted.
// LN=1: fused bias+ReLU+LayerNorm epilogue (conv1); LN=0: raw write (conv2)
template <int LN>
__global__ __launch_bounds__(256) void k_gather(const int* __restrict__ rowptr,
                                                const int2* __restrict__ cw,
                                                const float* __restrict__ dis,
                                                const ushort* __restrict__ feat,
                                                const float* __restrict__ b1,
                                                const float* __restrict__ gamma,
                                                const float* __restrict__ beta,
                                                ushort* __restrict__ outp) {
  int node = blockIdx.x * 4 + (threadIdx.x >> 6);
  if (node >= NN) return;
  int l = threadIdx.x & 63;
  int g = l >> 4;    // edge slot within wave
  int c16 = l & 15;  // 16-byte column chunk

  // issue self-row load early; consumed after the edge loop
  float di = dis[node];
  uint4 vSelf = ((const uint4*)(feat + ((size_t)node << 7)))[c16];

  float acc[8] = {};
  int e0 = rowptr[node], nE = rowptr[node + 1] - e0;
  int base = 0;
  for (; base + 8 <= nE; base += 8) {
    int2 cA = cw[e0 + base + g];
    int2 cB = cw[e0 + base + 4 + g];
    uint4 vA = ((const uint4*)(feat + ((size_t)cA.x << 7)))[c16];
    uint4 vB = ((const uint4*)(feat + ((size_t)cB.x << 7)))[c16];
    float wA = __int_as_float(cA.y), wB = __int_as_float(cB.y);
    acc[0] = fmaf(wA, bflo(vA.x), acc[0]); acc[1] = fmaf(wA, bfhi(vA.x), acc[1]);
    acc[2] = fmaf(wA, bflo(vA.y), acc[2]); acc[3] = fmaf(wA, bfhi(vA.y), acc[3]);
    acc[4] = fmaf(wA, bflo(vA.z), acc[4]); acc[5] = fmaf(wA, bfhi(vA.z), acc[5]);
    acc[6] = fmaf(wA, bflo(vA.w), acc[6]); acc[7] = fmaf(wA, bfhi(vA.w), acc[7]);
    acc[0] = fmaf(wB, bflo(vB.x), acc[0]); acc[1] = fmaf(wB, bfhi(vB.x), acc[1]);
    acc[2] = fmaf(wB, bflo(vB.y), acc[2]); acc[3] = fmaf(wB, bfhi(vB.y), acc[3]);
    acc[4] = fmaf(wB, bflo(vB.z), acc[4]); acc[5] = fmaf(wB, bfhi(vB.z), acc[5]);
    acc[6] = fmaf(wB, bflo(vB.w), acc[6]); acc[7] = fmaf(wB, bfhi(vB.w), acc[7]);
  }
  // tail (0..7 edges): slots base+g and base+4+g
#pragma unroll
  for (int t = 0; t < 2; ++t) {
    int idx = base + t * 4 + g;
    if (idx < nE) {
      int2 c0 = cw[e0 + idx];
      uint4 v = ((const uint4*)(feat + ((size_t)c0.x << 7)))[c16];
      float w0 = __int_as_float(c0.y);
      acc[0] = fmaf(w0, bflo(v.x), acc[0]); acc[1] = fmaf(w0, bfhi(v.x), acc[1]);
      acc[2] = fmaf(w0, bflo(v.y), acc[2]); acc[3] = fmaf(w0, bfhi(v.y), acc[3]);
      acc[4] = fmaf(w0, bflo(v.z), acc[4]); acc[5] = fmaf(w0, bfhi(v.z), acc[5]);
      acc[6] = fmaf(w0, bflo(v.w), acc[6]); acc[7] = fmaf(w0, bfhi(v.w), acc[7]);
    }
  }
  // reduce across the 4 edge-slot groups (bits 4,5 of lane)
#pragma unroll
  for (int j = 0; j < 8; ++j) {
    acc[j] += __shfl_xor(acc[j], 16);
    acc[j] += __shfl_xor(acc[j], 32);
  }
  // self-loop (post-reduction so it's added once)
  {
    float sw = di * di;
    acc[0] = fmaf(sw, bflo(vSelf.x), acc[0]); acc[1] = fmaf(sw, bfhi(vSelf.x), acc[1]);
    acc[2] = fmaf(sw, bflo(vSelf.y), acc[2]); acc[3] = fmaf(sw, bfhi(vSelf.y), acc[3]);
    acc[4] = fmaf(sw, bflo(vSelf.z), acc[4]); acc[5] = fmaf(sw, bfhi(vSelf.z), acc[5]);
    acc[6] = fmaf(sw, bflo(vSelf.w), acc[6]); acc[7] = fmaf(sw, bfhi(vSelf.w), acc[7]);
  }
  int cOff = c16 * 8;
  float o[8];
  if (LN) {
    float4 ba = *(const float4*)&b1[cOff];
    float4 bb = *(const float4*)&b1[cOff + 4];
    float a[8];
    a[0] = fmaxf(acc[0] + ba.x, 0.f); a[1] = fmaxf(acc[1] + ba.y, 0.f);
    a[2] = fmaxf(acc[2] + ba.z, 0.f); a[3] = fmaxf(acc[3] + ba.w, 0.f);
    a[4] = fmaxf(acc[4] + bb.x, 0.f); a[5] = fmaxf(acc[5] + bb.y, 0.f);
    a[6] = fmaxf(acc[6] + bb.z, 0.f); a[7] = fmaxf(acc[7] + bb.w, 0.f);
    float s = 0.f, sq = 0.f;
#pragma unroll
    for (int j = 0; j < 8; ++j) { s += a[j]; sq += a[j] * a[j]; }
#pragma unroll
    for (int m = 1; m < 16; m <<= 1) {
      s += __shfl_xor(s, m);
      sq += __shfl_xor(sq, m);
    }
    float mean = s * (1.f / 128.f);
    float var = sq * (1.f / 128.f) - mean * mean;
    float rstd = rsqrtf(var + EPSF);
    float4 ga = *(const float4*)&gamma[cOff];
    float4 gb = *(const float4*)&gamma[cOff + 4];
    float4 ea = *(const float4*)&beta[cOff];
    float4 eb = *(const float4*)&beta[cOff + 4];
    o[0] = (a[0] - mean) * rstd * ga.x + ea.x; o[1] = (a[1] - mean) * rstd * ga.y + ea.y;
    o[2] = (a[2] - mean) * rstd * ga.z + ea.z; o[3] = (a[3] - mean) * rstd * ga.w + ea.w;
    o[4] = (a[4] - mean) * rstd * gb.x + eb.x; o[5] = (a[5] - mean) * rstd * gb.y + eb.y;
    o[6] = (a[6] - mean) * rstd * gb.z + eb.z; o[7] = (a[7] - mean) * rstd * gb.w + eb.w;
  } else {
#pragma unroll
    for (int j = 0; j < 8; ++j) o[j] = acc[j];
  }
  if (g == 0) {
    uint4 p;
    p.x = pack2(o[0], o[1]); p.y = pack2(o[2], o[3]);
    p.z = pack2(o[4], o[5]); p.w = pack2(o[6], o[7]);
    ((uint4*)(outp + ((size_t)node << 7)))[c16] = p;
  }
}

extern "C" void kernel_launch(void* const* d_in, const int* in_sizes, int n_in,
                              void* d_out, int out_size, void* d_ws, size_t ws_size,
                              hipStream_t stream) {
  const float* x     = (const float*)d_in[0];
  const void*  ei    = d_in[1];
  const float* W1    = (const float*)d_in[2];
  const float* b1    = (const float*)d_in[3];
  const float* gamma = (const float*)d_in[4];
  const float* beta  = (const float*)d_in[5];
  const float* Wmu   = (const float*)d_in[6];
  const float* bmu   = (const float*)d_in[7];
  const float* Wlv   = (const float*)d_in[8];
  const float* blv   = (const float*)d_in[9];
  float* out = (float*)d_out;

  // workspace (4B words):
  // [flag 64][cnt N][rowptr N+16][dis N][bsum 256][boff 256][rank E]
  // [cw int2 E][t bf16 N*128][h bf16 N*128][t2 bf16 N*128]   ~48.6 MB
  int*   flag   = (int*)d_ws;
  int*   cnt    = flag + 64;
  int*   rowptr = cnt + NN;
  float* dis    = (float*)(rowptr + (NN + 16));
  int*   bsum   = (int*)(dis + NN);
  int*   boff   = bsum + 256;
  int*   rank   = boff + 256;
  size_t off32  = (size_t)(64 + NN + (NN + 16) + NN + 256 + 256 + EE);
  off32 = (off32 + 63) & ~(size_t)63;
  int2*  cw     = (int2*)((int*)d_ws + off32);
  ushort* t  = (ushort*)(cw + EE);
  ushort* h  = t + (size_t)NN * FF;
  ushort* t2 = h + (size_t)NN * FF;

  k_init<<<SCB, 256, 0, stream>>>(ei, flag, cnt);
  k_deg_rank<<<EBLK, 256, 0, stream>>>(ei, flag, cnt, rank);
  k_dis_part<<<SCB, 256, 0, stream>>>(cnt, dis, bsum);
  k_scan_tops<<<1, 256, 0, stream>>>(bsum, boff, rowptr);
  k_scan_write<<<SCB, 256, 0, stream>>>(cnt, boff, rowptr);
  k_scatter_gemm1<<<GBLK + EBLK, 256, 0, stream>>>(ei, flag, dis, rowptr, rank, cw,
                                                   x, W1, t);
  k_gather<1><<<(NN + 3) / 4, 256, 0, stream>>>(rowptr, cw, dis, t, b1, gamma, beta, h);
  k_gather<0><<<(NN + 3) / 4, 256, 0, stream>>>(rowptr, cw, dis, h, b1, gamma, beta, t2);
  k_gemm2<<<GBLK, 256, 0, stream>>>(t2, Wmu, bmu, Wlv, blv, out);
}